// Round 5
// baseline (84.596 us; speedup 1.0000x reference)
//
#include <hip/hip_runtime.h>
#include <hip/hip_bf16.h>

// SioConv: out[b,i,d] = Re(h[i]) where
//   a[b,l,d] = (re,im) * rsqrt(m2) * exp(-m2),  (re,im) = x[b,l,:] @ W_a rows 2d/2d+1
//   g[i] = a_i * (x_hat[i] + g[i+1])   (backward scan, g[L]=0)
//   out[i] = Re(g[i]) + Re(x_hat[i-1]) (i>=1), out[L-1] += x[b,L-1,d]
//   x_hat[0] = h0 (complex), x_hat[k] = x[b,k-1,d] (real)
//
// R5: SINGLE fused kernel (R4 post-mortem: 3 dispatches + 2-waves/CU gemm +
//     8-block scan all regressed; harness fill fixes ~45-50us of dur_us, so
//     dispatch count dominates the controllable part).
//     Block = (b, d-pair), 512 threads; thread (c,l) computes a[b,l,d0+c] by
//     direct-global GEMM (x rows via vector loads, W rows wave-uniform ->
//     s_load broadcast), keeps a in registers, then in-block Hillis-Steele
//     suffix scan over complex affine maps (R1's verified algorithm).

constexpr int B = 2, L = 256, D = 256, K = 256;

__global__ __launch_bounds__(512) void sioconv_fused_kernel(
    const float* __restrict__ x,    // [B, L, K]
    const float* __restrict__ W,    // [2D, K]
    const float* __restrict__ h0r,  // [D]
    const float* __restrict__ h0i,  // [D]
    float* __restrict__ out)        // [B, L, D]
{
    const int b  = blockIdx.x >> 7;          // 0..1
    const int dp = blockIdx.x & 127;         // d-pair
    const int t  = threadIdx.x;
    const int c  = t >> 8;                   // 0..1 (wave-uniform)
    const int l  = t & 255;                  // scan position / x row
    const int d  = 2 * dp + c;

    // ---------------- Phase 1: GEMM for a[b, l, d] ----------------
    const float4* x4 = (const float4*)(x + (size_t)(b * L + l) * K);  // per-lane row
    const float4* w4 = (const float4*)(W + (size_t)(2 * d) * K);      // wave-uniform

    float re = 0.f, im = 0.f;
#pragma unroll 8
    for (int k4 = 0; k4 < K / 4; ++k4) {
        const float4 xv = x4[k4];
        const float4 w0 = w4[k4];        // row 2d   (uniform -> scalar load)
        const float4 w1 = w4[k4 + 64];   // row 2d+1
        re += xv.x * w0.x + xv.y * w0.y + xv.z * w0.z + xv.w * w0.w;
        im += xv.x * w1.x + xv.y * w1.y + xv.z * w1.z + xv.w * w1.w;
    }

    const float m2 = re * re + im * im;
    const float s  = rsqrtf(m2) * expf(-m2);
    const float ar = re * s, ai = im * s;    // a[b,l,d] stays in registers

    // ---------------- Phase 2: suffix scan ----------------
    __shared__ float4 Ms[2][L];      // 8 KB: (Ar,Ai,Br,Bi) per column pos
    __shared__ float  xcol[2][L];    // 2 KB: xcol[c][l] = Re(xhat_l) for epilogue

    const size_t colbase = (size_t)b * L * D + d;

    float xr, xi;
    if (l == 0) { xr = h0r[d]; xi = h0i[d]; }
    else        { xr = x[colbase + (size_t)(l - 1) * D]; xi = 0.f; }
    xcol[c][l] = xr;   // consumed after scan barriers; safe

    // f_l = (A = a_l, B = a_l * xhat_l)
    float Ar = ar, Ai = ai;
    float Br = ar * xr - ai * xi;
    float Bi = ar * xi + ai * xr;

    // Hillis-Steele suffix scan: after all steps, (A,B)_l = f_l o ... o f_{L-1}
#pragma unroll
    for (int o = 1; o < L; o <<= 1) {
        Ms[c][l] = make_float4(Ar, Ai, Br, Bi);
        __syncthreads();
        if (l + o < L) {
            const float4 n = Ms[c][l + o];
            const float nAr = Ar * n.x - Ai * n.y;
            const float nAi = Ar * n.y + Ai * n.x;
            const float nBr = Ar * n.z - Ai * n.w + Br;
            const float nBi = Ar * n.w + Ai * n.z + Bi;
            Ar = nAr; Ai = nAi; Br = nBr; Bi = nBi;
        }
        __syncthreads();
    }

    // g_l = B_l (g[L]=0). Epilogue adds.
    float o_val = Br;
    if (l >= 2)      o_val += xcol[c][l - 1];                    // x[l-2]
    else if (l == 1) o_val += h0r[d];                            // Re(h0)
    if (l == L - 1)  o_val += x[colbase + (size_t)(L - 1) * D];  // + x[L-1]
    out[colbase + (size_t)l * D] = o_val;
}

extern "C" void kernel_launch(void* const* d_in, const int* in_sizes, int n_in,
                              void* d_out, int out_size, void* d_ws, size_t ws_size,
                              hipStream_t stream) {
    const float* x    = (const float*)d_in[0];   // B*L*D
    const float* W_a  = (const float*)d_in[1];   // 2D*D
    const float* h0r  = (const float*)d_in[2];   // D
    const float* h0i  = (const float*)d_in[3];   // D
    float* out = (float*)d_out;
    (void)d_ws; (void)ws_size;

    sioconv_fused_kernel<<<dim3(B * (D / 2)), dim3(512), 0, stream>>>(
        x, W_a, h0r, h0i, out);
}

// Round 6
// 69.435 us; speedup vs baseline: 1.2184x; 1.2184x over previous
//
#include <hip/hip_runtime.h>
#include <hip/hip_bf16.h>

// SioConv: out[b,i,d] = Re(h[i]) where
//   a[b,l,d] = (re,im) * rsqrt(m2) * exp(-m2),  (re,im) = x[b,l,:] @ W_a rows 2d/2d+1
//   g[i] = a_i * (x_hat[i] + g[i+1])   (backward scan, g[L]=0)
//   out[i] = Re(g[i]) + Re(x_hat[i-1]) (i>=1), out[L-1] += x[b,L-1,d]
//   x_hat[0] = h0 (complex), x_hat[k] = x[b,k-1,d] (real)
//
// R6: R3's two-kernel structure (fusion in R5 broke coalescing and regressed).
//  gemm_v4: tile 32l x 16d, 256 blocks, 2-way l register blocking -> 4
//           ds_read_b128 per 2 outputs (was 3 per 1). W-tile XOR-swizzled
//           (col ^ (dpair&7)) to turn a 4-way bank conflict into free 2-way.
//           a stored TRANSPOSED [b,d,l] so the scan's a-load coalesces.
//  scan:    R2's proven 512-block Hillis-Steele suffix scan; a-load now
//           coalesced; x column staged once into LDS (kills 2 of 3
//           uncoalesced column reads).

constexpr int B = 2, L = 256, D = 256, K = 256;
constexpr int TL = 32;        // l-rows per gemm block
constexpr int TD = 16;        // d-outputs per gemm block (32 W rows)
constexpr int PADW = 260;     // LDS row stride in floats (16B-aligned)

__global__ __launch_bounds__(256) void gemm_a_kernel(
    const float* __restrict__ x,    // [B, L, K]
    const float* __restrict__ W,    // [2D, K]
    float2* __restrict__ aT)        // [B, D, L]  (ws, transposed)
{
    const int dt = blockIdx.x;            // 0..15
    const int lt = blockIdx.y;            // 0..7
    const int b  = blockIdx.z;
    const int t  = threadIdx.x;           // 0..255
    const int l0 = lt * TL;
    const int d0 = dt * TD;

    __shared__ float xs[TL][PADW];        // 33.3 KB
    __shared__ float ws[2 * TD][PADW];    // 33.3 KB

    // Stage x rows l0..l0+31 (32 KB contiguous): 2048 float4, 8/thread.
    {
        const float4* src = (const float4*)(x + (size_t)(b * L + l0) * K);
#pragma unroll
        for (int j = 0; j < 8; ++j) {
            const int g = j * 256 + t;
            const int row = g >> 6, c4 = g & 63;
            *(float4*)&xs[row][c4 * 4] = src[g];
        }
    }
    // Stage W rows 2*d0 .. 2*d0+31, XOR-swizzled columns: logical c4 of row r
    // lives at physical c4 ^ ((r>>1)&7).
    {
        const float4* src = (const float4*)(W + (size_t)(2 * d0) * K);
#pragma unroll
        for (int j = 0; j < 8; ++j) {
            const int g = j * 256 + t;
            const int row = g >> 6, c4 = g & 63;
            *(float4*)&ws[row][(c4 ^ ((row >> 1) & 7)) * 4] = src[g];
        }
    }
    __syncthreads();

    const int dgrp = t & 15;              // d within tile
    const int lgrp = t >> 4;              // 0..15 -> l pair
    const int sw   = dgrp & 7;            // swizzle key for this thread's W rows

    float rr0 = 0.f, ii0 = 0.f, rr1 = 0.f, ii1 = 0.f;
#pragma unroll 8
    for (int k4 = 0; k4 < K / 4; ++k4) {
        const int kc = (k4 ^ sw) * 4;     // physical column of logical k4
        const float4 w0  = *(const float4*)&ws[2 * dgrp][kc];
        const float4 w1  = *(const float4*)&ws[2 * dgrp + 1][kc];
        const float4 xv0 = *(const float4*)&xs[2 * lgrp][k4 * 4];      // broadcast
        const float4 xv1 = *(const float4*)&xs[2 * lgrp + 1][k4 * 4];  // broadcast
        rr0 += xv0.x * w0.x + xv0.y * w0.y + xv0.z * w0.z + xv0.w * w0.w;
        ii0 += xv0.x * w1.x + xv0.y * w1.y + xv0.z * w1.z + xv0.w * w1.w;
        rr1 += xv1.x * w0.x + xv1.y * w0.y + xv1.z * w0.z + xv1.w * w0.w;
        ii1 += xv1.x * w1.x + xv1.y * w1.y + xv1.z * w1.z + xv1.w * w1.w;
    }

    const int d = d0 + dgrp;
#pragma unroll
    for (int i = 0; i < 2; ++i) {
        const float re = i ? rr1 : rr0, im = i ? ii1 : ii0;
        const float m2 = re * re + im * im;
        const float s  = rsqrtf(m2) * expf(-m2);
        // transposed store [b,d,l]; strided across lanes but tiny total txns
        aT[((size_t)b * D + d) * L + (l0 + 2 * lgrp + i)] = make_float2(re * s, im * s);
    }
}

// One block per (b,d) column; thread i owns scan position i.
__global__ __launch_bounds__(256) void scan_h_kernel(
    const float* __restrict__ x,    // [B, L, D]
    const float2* __restrict__ aT,  // [B, D, L]
    const float* __restrict__ h0r,  // [D]
    const float* __restrict__ h0i,  // [D]
    float* __restrict__ out)        // [B, L, D]
{
    const int b = blockIdx.x >> 8;
    const int d = blockIdx.x & 255;
    const int i = threadIdx.x;

    __shared__ float4 Ms[L];              // 4 KB
    __shared__ float  xcol[L];            // 1 KB: xcol[l] = x[b,l,d]

    const size_t colbase = (size_t)b * L * D + d;

    // Coalesced a-load (transposed layout) + one strided x column read.
    const float2 ai = aT[((size_t)b * D + d) * L + i];
    xcol[i] = x[colbase + (size_t)i * D];
    __syncthreads();

    float xr, xi;
    if (i == 0) { xr = h0r[d]; xi = h0i[d]; }
    else        { xr = xcol[i - 1]; xi = 0.f; }

    // f_i = (A = a_i, B = a_i * xhat_i)
    float Ar = ai.x, Ai = ai.y;
    float Br = ai.x * xr - ai.y * xi;
    float Bi = ai.x * xi + ai.y * xr;

#pragma unroll
    for (int o = 1; o < L; o <<= 1) {
        Ms[i] = make_float4(Ar, Ai, Br, Bi);
        __syncthreads();
        if (i + o < L) {
            const float4 n = Ms[i + o];
            const float nAr = Ar * n.x - Ai * n.y;
            const float nAi = Ar * n.y + Ai * n.x;
            const float nBr = Ar * n.z - Ai * n.w + Br;
            const float nBi = Ar * n.w + Ai * n.z + Bi;
            Ar = nAr; Ai = nAi; Br = nBr; Bi = nBi;
        }
        __syncthreads();
    }

    // g_i = B_i (g[L]=0). Epilogue from LDS copies.
    float o_val = Br;
    if (i >= 2)      o_val += xcol[i - 2];
    else if (i == 1) o_val += h0r[d];
    if (i == L - 1)  o_val += xcol[L - 1];
    out[colbase + (size_t)i * D] = o_val;
}

extern "C" void kernel_launch(void* const* d_in, const int* in_sizes, int n_in,
                              void* d_out, int out_size, void* d_ws, size_t ws_size,
                              hipStream_t stream) {
    const float* x    = (const float*)d_in[0];   // B*L*D
    const float* W_a  = (const float*)d_in[1];   // 2D*D
    const float* h0r  = (const float*)d_in[2];   // D
    const float* h0i  = (const float*)d_in[3];   // D
    float* out = (float*)d_out;
    float2* aT = (float2*)d_ws;                  // B*D*L float2 = 1 MiB

    gemm_a_kernel<<<dim3(D / TD, L / TL, B), dim3(256), 0, stream>>>(x, W_a, aT);
    scan_h_kernel<<<dim3(B * D), dim3(256), 0, stream>>>(x, aT, h0r, h0i, out);
}